// Round 1
// baseline (203.519 us; speedup 1.0000x reference)
//
#include <hip/hip_runtime.h>
#include <hip/hip_bf16.h>
#include <math.h>

// Problem constants: B=8, C=64, H=256, W=256
static constexpr int kC = 64;
static constexpr int kH = 256;
static constexpr int kW = 256;
static constexpr int kPlane = kH * kW;   // 65536

// Fixed stencils (same normalization as reference)
__constant__ float K_SX[9]  = {-0.125f, 0.0f, 0.125f,  -0.25f, 0.0f, 0.25f,  -0.125f, 0.0f, 0.125f};
__constant__ float K_SY[9]  = {-0.125f, -0.25f, -0.125f,  0.0f, 0.0f, 0.0f,  0.125f, 0.25f, 0.125f};
__constant__ float K_LAP[9] = {0.0f, -1.0f/6.0f, 0.0f,  -1.0f/6.0f, 4.0f/6.0f, -1.0f/6.0f,  0.0f, -1.0f/6.0f, 0.0f};
__constant__ float K_CS[9]  = {-1.0f/9.0f, -1.0f/9.0f, -1.0f/9.0f,  -1.0f/9.0f, 8.0f/9.0f, -1.0f/9.0f,  -1.0f/9.0f, -1.0f/9.0f, -1.0f/9.0f};

// ---------------- Kernel A: global average pool per (b,c) ----------------
__global__ __launch_bounds__(256) void pool_kernel(const float* __restrict__ x,
                                                   float* __restrict__ pooled) {
    const int bc = blockIdx.x;                      // 0..511
    const float4* p = (const float4*)(x + (size_t)bc * kPlane);
    float s = 0.0f;
    for (int i = threadIdx.x; i < kPlane / 4; i += 256) {
        float4 v = p[i];
        s += (v.x + v.y) + (v.z + v.w);
    }
    // wave (64-lane) reduce
    for (int off = 32; off; off >>= 1) s += __shfl_down(s, off);
    __shared__ float red[4];
    if ((threadIdx.x & 63) == 0) red[threadIdx.x >> 6] = s;
    __syncthreads();
    if (threadIdx.x == 0)
        pooled[bc] = (red[0] + red[1] + red[2] + red[3]) * (1.0f / (float)kPlane);
}

// ---------- Kernel B: SE attention MLP + combined 3x3 kernels -------------
__global__ __launch_bounds__(256) void att_wc_kernel(
    const float* __restrict__ pooled,   // [8][64]
    const float* __restrict__ idg_w,    // [64][9]
    const float* __restrict__ van_w,    // [64][9]
    const float* __restrict__ w1,       // [16][64]
    const float* __restrict__ b1,       // [16]
    const float* __restrict__ w2,       // [384][16]
    const float* __restrict__ b2,       // [384]
    float* __restrict__ wc_out)         // [8][64][9]
{
    __shared__ float sh[8][16];
    __shared__ float satt[8 * 384];
    const int t = threadIdx.x;

    if (t < 128) {
        const int b = t >> 4, j = t & 15;
        float acc = b1[j];
        const float* wr = w1 + j * 64;
        const float* pr = pooled + b * 64;
        #pragma unroll 8
        for (int c = 0; c < 64; ++c) acc += wr[c] * pr[c];
        sh[b][j] = fmaxf(acc, 0.0f);
    }
    __syncthreads();

    for (int i = t; i < 8 * 384; i += 256) {
        const int b = i / 384, k = i - b * 384;
        float acc = b2[k];
        const float* wr = w2 + k * 16;
        #pragma unroll
        for (int j = 0; j < 16; ++j) acc += wr[j] * sh[b][j];
        satt[i] = 1.0f / (1.0f + expf(-acc));
    }
    __syncthreads();

    // Wc[b][c][k] = a0*idg + a1*CS + a2*SX + a3*SY + a4*LAP + a5*van
    for (int i = t; i < 8 * 64 * 9; i += 256) {
        const int b = i / 576;
        const int r = i - b * 576;
        const int c = r / 9;
        const int k = r - c * 9;
        const float* ab = satt + b * 384;
        float v = ab[0 * 64 + c] * idg_w[c * 9 + k]
                + ab[1 * 64 + c] * K_CS[k]
                + ab[2 * 64 + c] * K_SX[k]
                + ab[3 * 64 + c] * K_SY[k]
                + ab[4 * 64 + c] * K_LAP[k]
                + ab[5 * 64 + c] * van_w[c * 9 + k];
        wc_out[i] = v;
    }
}

// ------ Kernel C: fused depthwise(combined) conv + 1x1 fusion conv --------
// Tile: 32 (W) x 2 (H) pixels = 64 px; block = 256 threads.
// Phase 1: each wave computes 16 channels' dw-conv for the 64 px -> LDS.
// Phase 2: 64(o) x 64(px) fp32 GEMM over c, 4x4 register tile per thread.
__global__ __launch_bounds__(256) void fused_dw_mix_kernel(
    const float* __restrict__ x,       // [8][64][256][256]
    const float* __restrict__ wc,      // [8][64][9]
    const float* __restrict__ fus_w,   // [64][64]  (o, c)
    const float* __restrict__ fus_b,   // [64]
    float* __restrict__ out)           // [8][64][256][256]
{
    __shared__ float s_fw[64 * 64];    // [c][o]  (transposed fus_w)
    __shared__ float s_dw[64 * 64];    // [c][p]
    __shared__ float s_wc[64 * 9];

    const int t  = threadIdx.x;
    const int b  = blockIdx.z;
    const int y0 = blockIdx.y * 2;
    const int x0 = blockIdx.x * 32;

    // stage fus_w transposed, and this batch's combined kernels
    for (int i = t; i < 4096; i += 256) {
        const int o = i >> 6, c = i & 63;
        s_fw[c * 64 + o] = fus_w[i];
    }
    for (int i = t; i < 576; i += 256) s_wc[i] = wc[b * 576 + i];
    __syncthreads();

    // ---------------- phase 1: depthwise conv into LDS ----------------
    const int p  = t & 63;
    const int px = p & 31;
    const int py = p >> 5;
    const int g  = t >> 6;             // wave id: channels g*16..g*16+15
    const int yy = y0 + py;
    const int xx = x0 + px;

    const float* xb = x + (size_t)b * kC * kPlane;
    const bool interior = (y0 >= 1) && (y0 + 2 <= 255) && (x0 >= 1) && (x0 + 32 <= 255);

    if (interior) {
        #pragma unroll 4
        for (int j = 0; j < 16; ++j) {
            const int c = g * 16 + j;
            const float* xc = xb + (size_t)c * kPlane + yy * kW + xx;
            const float* w9 = &s_wc[c * 9];
            float acc = w9[0] * xc[-kW - 1] + w9[1] * xc[-kW] + w9[2] * xc[-kW + 1]
                      + w9[3] * xc[-1]      + w9[4] * xc[0]   + w9[5] * xc[1]
                      + w9[6] * xc[kW - 1]  + w9[7] * xc[kW]  + w9[8] * xc[kW + 1];
            s_dw[c * 64 + p] = acc;
        }
    } else {
        #pragma unroll 4
        for (int j = 0; j < 16; ++j) {
            const int c = g * 16 + j;
            const float* xc = xb + (size_t)c * kPlane;
            const float* w9 = &s_wc[c * 9];
            float acc = 0.0f;
            #pragma unroll
            for (int dy = -1; dy <= 1; ++dy) {
                #pragma unroll
                for (int dx = -1; dx <= 1; ++dx) {
                    const int Y = yy + dy, X = xx + dx;
                    const float v = ((unsigned)Y < (unsigned)kH && (unsigned)X < (unsigned)kW)
                                        ? xc[Y * kW + X] : 0.0f;
                    acc += w9[(dy + 1) * 3 + (dx + 1)] * v;
                }
            }
            s_dw[c * 64 + p] = acc;
        }
    }
    __syncthreads();

    // ---------------- phase 2: 64x64 GEMM (o x p over c) ----------------
    const int to = t >> 4;   // 0..15 -> o block of 4
    const int tp = t & 15;   // 0..15 -> p block of 4
    float acc[4][4];
    #pragma unroll
    for (int i = 0; i < 4; ++i)
        #pragma unroll
        for (int jj = 0; jj < 4; ++jj) acc[i][jj] = 0.0f;

    const float4* fw4 = (const float4*)s_fw;
    const float4* dw4 = (const float4*)s_dw;
    #pragma unroll 8
    for (int c = 0; c < 64; ++c) {
        const float4 a = fw4[c * 16 + to];
        const float4 d = dw4[c * 16 + tp];
        acc[0][0] += a.x * d.x; acc[0][1] += a.x * d.y; acc[0][2] += a.x * d.z; acc[0][3] += a.x * d.w;
        acc[1][0] += a.y * d.x; acc[1][1] += a.y * d.y; acc[1][2] += a.y * d.z; acc[1][3] += a.y * d.w;
        acc[2][0] += a.z * d.x; acc[2][1] += a.z * d.y; acc[2][2] += a.z * d.z; acc[2][3] += a.z * d.w;
        acc[3][0] += a.w * d.x; acc[3][1] += a.w * d.y; acc[3][2] += a.w * d.z; acc[3][3] += a.w * d.w;
    }

    // epilogue: add bias, write float4 (4 consecutive px in one row)
    const int pb  = tp * 4;
    const int opy = pb >> 5;
    const int opx = pb & 31;
    #pragma unroll
    for (int i = 0; i < 4; ++i) {
        const int o = to * 4 + i;
        const float bias = fus_b[o];
        float4 v;
        v.x = acc[i][0] + bias;
        v.y = acc[i][1] + bias;
        v.z = acc[i][2] + bias;
        v.w = acc[i][3] + bias;
        *(float4*)(out + (size_t)(b * kC + o) * kPlane + (size_t)(y0 + opy) * kW + (x0 + opx)) = v;
    }
}

extern "C" void kernel_launch(void* const* d_in, const int* in_sizes, int n_in,
                              void* d_out, int out_size, void* d_ws, size_t ws_size,
                              hipStream_t stream) {
    const float* x     = (const float*)d_in[0];
    const float* idg_w = (const float*)d_in[1];
    const float* van_w = (const float*)d_in[2];
    const float* w1    = (const float*)d_in[3];
    const float* b1    = (const float*)d_in[4];
    const float* w2    = (const float*)d_in[5];
    const float* b2    = (const float*)d_in[6];
    const float* fw    = (const float*)d_in[7];
    const float* fb    = (const float*)d_in[8];
    float* out = (float*)d_out;

    float* wsf    = (float*)d_ws;
    float* pooled = wsf;          // 512 floats
    float* wcbuf  = wsf + 512;    // 4608 floats

    hipLaunchKernelGGL(pool_kernel, dim3(512), dim3(256), 0, stream, x, pooled);
    hipLaunchKernelGGL(att_wc_kernel, dim3(1), dim3(256), 0, stream,
                       pooled, idg_w, van_w, w1, b1, w2, b2, wcbuf);
    hipLaunchKernelGGL(fused_dw_mix_kernel, dim3(kW / 32, kH / 2, 8), dim3(256), 0, stream,
                       x, wcbuf, fw, fb, out);
}